// Round 8
// baseline (112.690 us; speedup 1.0000x reference)
//
#include <hip/hip_runtime.h>
#include <stdint.h>

// ---------------------------------------------------------------------------
// VQ-VAE VectorQuantizer forward (MI355X):
//   out  = encoderout (faithful source bug)
//   loss_sum = sum_all x^2 + sum_m min_n (||e_n||^2 - 2 x_m.e_n)
//   cbl = loss_sum/ELEMS ; comm = cbl ; loss = 1.25*cbl
// enc [32,256,32,32] f32 NCHW, codebook [1024,256] f32.
// R9 = R8 + store-side of the enc->out copy moved INTO the K-loop:
//   phase A = load+sumsq+transpose only (no stores in its barrier drain);
//   K-loop stores one float4/thread/chunk, fed by a rolling 1-chunk-ahead
//   re-load of enc (L2/L3-hot). Overlaps the 32MB HBM write with the
//   L2-bound MFMA loop. +5 transient regs (R6's spill was +16 persistent).
//   R8 diagnosis: all blocks resident from t=0 -> lockstep phases, memory
//   phases never covered by compute; this breaks the in-block serialization.
// ---------------------------------------------------------------------------

#define EMB 256
#define ELEMS 8388608   // 32*256*32*32
#define NBLK 512

typedef __bf16 bf16x8 __attribute__((ext_vector_type(8)));
typedef float  f32x4  __attribute__((ext_vector_type(4)));

union Frag { uint4 u4; bf16x8 v; };

__device__ __forceinline__ unsigned short f2bf(float f) {
    unsigned u = __float_as_uint(f);
    u += 0x7FFFu + ((u >> 16) & 1u);   // RNE
    return (unsigned short)(u >> 16);
}

// ---------------------------------------------------------------------------
// prep: codebook f32 [1024][256] -> bf16 fragment-ordered global layout:
//   uint4 granule index = nc*2048 + ks*256 + (n&63)*4 + q
//   (nc = n>>6 chunk of 64 codes; ks = K-step 0..7; q = 8-elem K-quad)
// esq[n] = ||e_n||^2. Also zeroes accum + done.
// ---------------------------------------------------------------------------
__global__ __launch_bounds__(256) void vq_prep(const float* __restrict__ cb,
                                               uint2* __restrict__ cbswz,
                                               float* __restrict__ esq,
                                               float* __restrict__ accum,
                                               unsigned* __restrict__ done) {
    if (blockIdx.x == 0 && threadIdx.x == 0) { accum[0] = 0.f; done[0] = 0u; }

    const int tid  = threadIdx.x;
    const int w    = tid >> 6;
    const int lane = tid & 63;
    const int n    = blockIdx.x * 4 + w;

    const float4* row = (const float4*)(cb + n * EMB);
    float4 v = row[lane];                       // k = 4*lane .. 4*lane+3

    float s = v.x * v.x + v.y * v.y + v.z * v.z + v.w * v.w;
    #pragma unroll
    for (int m = 1; m <= 32; m <<= 1) s += __shfl_xor(s, m);
    if (lane == 0) esq[n] = s;

    unsigned lo = (unsigned)f2bf(v.x) | ((unsigned)f2bf(v.y) << 16);
    unsigned hi = (unsigned)f2bf(v.z) | ((unsigned)f2bf(v.w) << 16);
    const int kc = lane >> 1;          // 16B K-granule 0..31 (8 bf16)
    const int h  = lane & 1;           // low/high uint2 of the granule
    const unsigned idx4 = ((unsigned)(n >> 6) << 11) + ((unsigned)(kc >> 2) << 8)
                        + ((unsigned)(n & 63) << 2) + (unsigned)(kc & 3);
    cbswz[idx4 * 2 + h] = make_uint2(lo, hi);
}

// ---------------------------------------------------------------------------
// main: block = 64 hw-rows of one image; 4 waves; grid 512 (2 blocks/CU).
// Each wave: all 64 rows (mi=0..3), codes w*16..w*16+15 of each 64-chunk.
// ---------------------------------------------------------------------------

#define CHUNK_BODY(nc_, LOADNEXT_) do {                                        \
    /* copy-dribble: store chunk nc (loaded a chunk ago), load next */         \
    *(f32x4*)(outB + (size_t)(kg * 16 + (nc_)) * 1024 + q4 * 4) = cp;          \
    if (LOADNEXT_)                                                             \
        cp = *(const f32x4*)(encB + (size_t)(kg * 16 + (nc_) + 1) * 1024 + q4 * 4); \
    f32x4 _a0 = (f32x4){0.f,0.f,0.f,0.f};                                      \
    f32x4 _a1 = (f32x4){0.f,0.f,0.f,0.f};                                      \
    f32x4 _a2 = (f32x4){0.f,0.f,0.f,0.f};                                      \
    f32x4 _a3 = (f32x4){0.f,0.f,0.f,0.f};                                      \
    _Pragma("unroll")                                                          \
    for (int _ks = 0; _ks < 8; ++_ks) {                                        \
        bf16x8 _bv = bfr[_ks].v;                                               \
        _a0 = __builtin_amdgcn_mfma_f32_16x16x32_bf16(afr[0][_ks], _bv, _a0, 0, 0, 0); \
        _a1 = __builtin_amdgcn_mfma_f32_16x16x32_bf16(afr[1][_ks], _bv, _a1, 0, 0, 0); \
        _a2 = __builtin_amdgcn_mfma_f32_16x16x32_bf16(afr[2][_ks], _bv, _a2, 0, 0, 0); \
        _a3 = __builtin_amdgcn_mfma_f32_16x16x32_bf16(afr[3][_ks], _bv, _a3, 0, 0, 0); \
        if (LOADNEXT_)   /* rolling prefetch: chunk nc+1, same frag slot */    \
            bfr[_ks].u4 = pc[((nc_) + 1) * 2048 + _ks * 256];                  \
    }                                                                          \
    const float _eq = esq[(nc_) * 64 + nl];                                    \
    _Pragma("unroll")                                                          \
    for (int _r2 = 0; _r2 < 4; ++_r2) {                                        \
        rmin[0][_r2] = fminf(rmin[0][_r2], fmaf(-2.f, _a0[_r2], _eq));         \
        rmin[1][_r2] = fminf(rmin[1][_r2], fmaf(-2.f, _a1[_r2], _eq));         \
        rmin[2][_r2] = fminf(rmin[2][_r2], fmaf(-2.f, _a2[_r2], _eq));         \
        rmin[3][_r2] = fminf(rmin[3][_r2], fmaf(-2.f, _a3[_r2], _eq));         \
    } } while (0)

__global__ __launch_bounds__(256, 2)
void vq_main(const float* __restrict__ enc,
             const uint4* __restrict__ cbswz,
             const float* __restrict__ esq,
             float* __restrict__ out,
             float* __restrict__ accum,
             unsigned* __restrict__ done) {
    __shared__ uint4 As[2048];          // 32 KB: 64 rows x 512B swizzled (A transpose only)
    __shared__ float dmin[4][64];
    __shared__ float partsA[4];

    const int tid  = threadIdx.x;
    const int w    = tid >> 6;          // wave 0..3 = code subgroup
    const int lane = tid & 63;
    const int q    = lane >> 4;         // quad 0..3
    const int c    = lane & 15;

    const int b   = blockIdx.x >> 4;            // image
    const int hw0 = (blockIdx.x & 15) << 6;     // 64-row slab
    const float* encB = enc + (size_t)b * 262144 + hw0;
    float*       outB = out + (size_t)b * 262144 + hw0;

    const int nl = w * 16 + c;          // this lane's code within each 64-chunk
    const uint4* pc = cbswz + (size_t)(nl * 4 + q);   // per-lane frag base

    // ---- phase A: load enc (16 float4/thread, 16-deep MLP), sum(x^2),
    //      bf16 transpose into swizzled As. NO stores here: the out-copy's
    //      store side dribbles through the K-loop (overlaps HBM write with
    //      the L2-bound MFMA loop).
    const int q4 = tid & 15;            // hw quad (4 hw rows)
    const int kg = tid >> 4;            // 0..15 -> ch0 = kg*16
    float sx = 0.f;
    {
        f32x4 vh[16];
        #pragma unroll
        for (int j = 0; j < 16; ++j)
            vh[j] = *(const f32x4*)(encB + (size_t)(kg * 16 + j) * 1024 + q4 * 4);
        #pragma unroll
        for (int j = 0; j < 16; ++j) {
            #pragma unroll
            for (int i2 = 0; i2 < 4; ++i2) sx = fmaf(vh[j][i2], vh[j][i2], sx);
        }
        #pragma unroll
        for (int i = 0; i < 4; ++i) {   // row r = q4*4+i; chunks 2kg, 2kg+1
            unsigned short us[16];
            #pragma unroll
            for (int j = 0; j < 16; ++j) us[j] = f2bf(vh[j][i]);
            uint4 pk0, pk1;
            pk0.x = (unsigned)us[0]  | ((unsigned)us[1]  << 16);
            pk0.y = (unsigned)us[2]  | ((unsigned)us[3]  << 16);
            pk0.z = (unsigned)us[4]  | ((unsigned)us[5]  << 16);
            pk0.w = (unsigned)us[6]  | ((unsigned)us[7]  << 16);
            pk1.x = (unsigned)us[8]  | ((unsigned)us[9]  << 16);
            pk1.y = (unsigned)us[10] | ((unsigned)us[11] << 16);
            pk1.z = (unsigned)us[12] | ((unsigned)us[13] << 16);
            pk1.w = (unsigned)us[14] | ((unsigned)us[15] << 16);
            const int r = q4 * 4 + i;
            As[r * 32 + ((2 * kg + 0) ^ (r & 7))] = pk0;
            As[r * 32 + ((2 * kg + 1) ^ (r & 7))] = pk1;
        }
    }

    // ---- prologue: chunk-0 B frags + chunk-0 copy-load; the phase-A
    //      barrier's vmcnt(0) drain doubles as their completion wait.
    Frag bfr[8];
    #pragma unroll
    for (int ks = 0; ks < 8; ++ks) bfr[ks].u4 = pc[ks * 256];
    f32x4 cp = *(const f32x4*)(encB + (size_t)(kg * 16) * 1024 + q4 * 4);

    #pragma unroll
    for (int m = 1; m <= 32; m <<= 1) sx += __shfl_xor(sx, m);
    if (lane == 0) partsA[w] = sx;
    __syncthreads();                    // As ready + chunk-0 B/copy loaded

    // ---- A fragments: 64 rows x full K into registers (mi=4) ----
    bf16x8 afr[4][8];
    #pragma unroll
    for (int mi = 0; mi < 4; ++mi) {
        const int r = mi * 16 + c;
        #pragma unroll
        for (int ks = 0; ks < 8; ++ks) {
            Frag fa; fa.u4 = As[r * 32 + ((ks * 4 + q) ^ (r & 7))];
            afr[mi][ks] = fa.v;
        }
    }

    float rmin[4][4];
    #pragma unroll
    for (int mi = 0; mi < 4; ++mi)
        #pragma unroll
        for (int r2 = 0; r2 < 4; ++r2) rmin[mi][r2] = 1e30f;

    // ---- K-loop: 16 chunks of 64 codes; NO barriers, NO LDS; rolling
    //      global->reg prefetch (B + copy) one chunk ahead. ----
    for (int nc = 0; nc < 15; ++nc) CHUNK_BODY(nc, 1);
    CHUNK_BODY(15, 0);

    // min across the 16 code-columns (xor over c bits), then per-row mins
    #pragma unroll
    for (int mi = 0; mi < 4; ++mi)
        #pragma unroll
        for (int r2 = 0; r2 < 4; ++r2) {
            float x = rmin[mi][r2];
            x = fminf(x, __shfl_xor(x, 1));
            x = fminf(x, __shfl_xor(x, 2));
            x = fminf(x, __shfl_xor(x, 4));
            x = fminf(x, __shfl_xor(x, 8));
            rmin[mi][r2] = x;
        }
    if (c == 0) {
        #pragma unroll
        for (int mi = 0; mi < 4; ++mi)
            #pragma unroll
            for (int r2 = 0; r2 < 4; ++r2)
                dmin[w][mi * 16 + q * 4 + r2] = rmin[mi][r2];
    }
    __syncthreads();

    if (tid < 64) {
        float vr = fminf(fminf(dmin[0][tid], dmin[1][tid]),
                         fminf(dmin[2][tid], dmin[3][tid]));
        #pragma unroll
        for (int m = 1; m <= 32; m <<= 1) vr += __shfl_xor(vr, m);
        if (tid == 0) {
            float s = vr + partsA[0] + partsA[1] + partsA[2] + partsA[3];
            atomicAdd(accum, s);
            __threadfence();                          // release our add
            unsigned prev = atomicAdd(done, 1u);      // device-scope ticket
            if (prev == NBLK - 1) {
                float tot = atomicAdd(accum, 0.0f);   // coherent read of total
                float cbl = tot * (1.0f / (float)ELEMS);
                out[ELEMS + 0] = 1.25f * cbl;   // loss = cbl + BETA*cbl
                out[ELEMS + 1] = cbl;           // codebook_loss
                out[ELEMS + 2] = cbl;           // commitment_loss
            }
        }
    }
}

extern "C" void kernel_launch(void* const* d_in, const int* in_sizes, int n_in,
                              void* d_out, int out_size, void* d_ws, size_t ws_size,
                              hipStream_t stream) {
    const float* enc = (const float*)d_in[0];
    const float* cb  = (const float*)d_in[1];
    float* out = (float*)d_out;

    float*    accum = (float*)d_ws;                    // 4 B
    unsigned* done  = (unsigned*)((char*)d_ws + 64);   // 4 B
    float*    esq   = (float*)((char*)d_ws + 256);     // 4 KB
    uint2*    cbswz = (uint2*)((char*)d_ws + 8192);    // 512 KB

    vq_prep<<<dim3(256), dim3(256), 0, stream>>>(cb, cbswz, esq, accum, done);
    vq_main<<<dim3(NBLK), dim3(256), 0, stream>>>(enc, (const uint4*)cbswz, esq,
                                                  out, accum, done);
}

// Round 10
// 109.170 us; speedup vs baseline: 1.0322x; 1.0322x over previous
//
#include <hip/hip_runtime.h>
#include <stdint.h>

// ---------------------------------------------------------------------------
// VQ-VAE VectorQuantizer forward (MI355X):
//   out  = encoderout (faithful source bug)
//   loss_sum = sum_all x^2 + sum_m min_n (||e_n||^2 - 2 x_m.e_n)
//   cbl = loss_sum/ELEMS ; comm = cbl ; loss = 1.25*cbl
// enc [32,256,32,32] f32 NCHW, codebook [1024,256] f32.
// R11 = R1 geometry x R8 mechanism. R10 post-mortem: prep-gate deadlock
// (grid-wide co-residency assumed; G16 violation) -> fusion shelved.
// Ledger: R1 (512thr/128-row, LDS-B, 109.1) vs R8 (256thr/64-row, reg-B,
// 111.2). This kernel: grid 256 x 512 threads, 128-row slab (halves K-loop
// L2 codebook traffic 256->128 MB) + barrier-free global->reg B K-loop
// (R8's). Per-wave regs identical to R8's proven build (~116 VGPR).
// LDS 66.6 KB, 1 block/CU, 2 waves/SIMD. 2 dispatches, no NT hints.
// ---------------------------------------------------------------------------

#define EMB 256
#define ELEMS 8388608   // 32*256*32*32
#define NBLK 256

typedef __bf16 bf16x8 __attribute__((ext_vector_type(8)));
typedef float  f32x4  __attribute__((ext_vector_type(4)));

union Frag { uint4 u4; bf16x8 v; };

__device__ __forceinline__ unsigned short f2bf(float f) {
    unsigned u = __float_as_uint(f);
    u += 0x7FFFu + ((u >> 16) & 1u);   // RNE
    return (unsigned short)(u >> 16);
}

// ---------------------------------------------------------------------------
// prep: codebook f32 [1024][256] -> bf16 fragment-ordered global layout:
//   uint4 granule index = nc*2048 + ks*256 + (n&63)*4 + q
//   (nc = n>>6 chunk of 64 codes; ks = K-step 0..7; q = 8-elem K-quad)
// esq[n] = ||e_n||^2. Also zeroes accum + done.
// ---------------------------------------------------------------------------
__global__ __launch_bounds__(256) void vq_prep(const float* __restrict__ cb,
                                               uint2* __restrict__ cbswz,
                                               float* __restrict__ esq,
                                               float* __restrict__ accum,
                                               unsigned* __restrict__ done) {
    if (blockIdx.x == 0 && threadIdx.x == 0) { accum[0] = 0.f; done[0] = 0u; }

    const int tid  = threadIdx.x;
    const int w    = tid >> 6;
    const int lane = tid & 63;
    const int n    = blockIdx.x * 4 + w;

    const float4* row = (const float4*)(cb + n * EMB);
    float4 v = row[lane];                       // k = 4*lane .. 4*lane+3

    float s = v.x * v.x + v.y * v.y + v.z * v.z + v.w * v.w;
    #pragma unroll
    for (int m = 1; m <= 32; m <<= 1) s += __shfl_xor(s, m);
    if (lane == 0) esq[n] = s;

    unsigned lo = (unsigned)f2bf(v.x) | ((unsigned)f2bf(v.y) << 16);
    unsigned hi = (unsigned)f2bf(v.z) | ((unsigned)f2bf(v.w) << 16);
    const int kc = lane >> 1;          // 16B K-granule 0..31 (8 bf16)
    const int h  = lane & 1;           // low/high uint2 of the granule
    const unsigned idx4 = ((unsigned)(n >> 6) << 11) + ((unsigned)(kc >> 2) << 8)
                        + ((unsigned)(n & 63) << 2) + (unsigned)(kc & 3);
    cbswz[idx4 * 2 + h] = make_uint2(lo, hi);
}

// ---------------------------------------------------------------------------
// main: block = 128 hw-rows of one image; 8 waves; grid 256 (1 block/CU).
// wm = w>>2: 64-row group; wn = w&3: 16-code subgroup. Each wave: mi=0..3
// over its 64 rows, codes wn*16..wn*16+15 of each 64-code chunk.
// ---------------------------------------------------------------------------

#define CHUNK_BODY(nc_, LOADNEXT_) do {                                        \
    f32x4 _a0 = (f32x4){0.f,0.f,0.f,0.f};                                      \
    f32x4 _a1 = (f32x4){0.f,0.f,0.f,0.f};                                      \
    f32x4 _a2 = (f32x4){0.f,0.f,0.f,0.f};                                      \
    f32x4 _a3 = (f32x4){0.f,0.f,0.f,0.f};                                      \
    _Pragma("unroll")                                                          \
    for (int _ks = 0; _ks < 8; ++_ks) {                                        \
        bf16x8 _bv = bfr[_ks].v;                                               \
        _a0 = __builtin_amdgcn_mfma_f32_16x16x32_bf16(afr[0][_ks], _bv, _a0, 0, 0, 0); \
        _a1 = __builtin_amdgcn_mfma_f32_16x16x32_bf16(afr[1][_ks], _bv, _a1, 0, 0, 0); \
        _a2 = __builtin_amdgcn_mfma_f32_16x16x32_bf16(afr[2][_ks], _bv, _a2, 0, 0, 0); \
        _a3 = __builtin_amdgcn_mfma_f32_16x16x32_bf16(afr[3][_ks], _bv, _a3, 0, 0, 0); \
        if (LOADNEXT_)   /* rolling prefetch: chunk nc+1, same frag slot */    \
            bfr[_ks].u4 = pc[((nc_) + 1) * 2048 + _ks * 256];                  \
    }                                                                          \
    const float _eq = esq[(nc_) * 64 + nl];                                    \
    _Pragma("unroll")                                                          \
    for (int _r2 = 0; _r2 < 4; ++_r2) {                                        \
        rmin[0][_r2] = fminf(rmin[0][_r2], fmaf(-2.f, _a0[_r2], _eq));         \
        rmin[1][_r2] = fminf(rmin[1][_r2], fmaf(-2.f, _a1[_r2], _eq));         \
        rmin[2][_r2] = fminf(rmin[2][_r2], fmaf(-2.f, _a2[_r2], _eq));         \
        rmin[3][_r2] = fminf(rmin[3][_r2], fmaf(-2.f, _a3[_r2], _eq));         \
    } } while (0)

__global__ __launch_bounds__(512, 2)
void vq_main(const float* __restrict__ enc,
             const uint4* __restrict__ cbswz,
             const float* __restrict__ esq,
             float* __restrict__ out,
             float* __restrict__ accum,
             unsigned* __restrict__ done) {
    __shared__ uint4 As[4096];          // 64 KB: 128 rows x 512B swizzled (A transpose only)
    __shared__ float dmin[4][128];
    __shared__ float partsA[8];
    __shared__ float partsB[2];

    const int tid  = threadIdx.x;
    const int w    = tid >> 6;          // wave 0..7
    const int lane = tid & 63;
    const int q    = lane >> 4;         // quad 0..3
    const int c    = lane & 15;
    const int wm   = w >> 2;            // 0..1 (64-row group)
    const int wn   = w & 3;             // 0..3 (16-code subgroup)

    const int b   = blockIdx.x >> 3;            // image
    const int hw0 = (blockIdx.x & 7) << 7;      // 128-row slab
    const float* encB = enc + (size_t)b * 262144 + hw0;
    float*       outB = out + (size_t)b * 262144 + hw0;

    const int nl = wn * 16 + c;         // this lane's code within each 64-chunk
    const uint4* pc = cbswz + (size_t)(nl * 4 + q);   // per-lane frag base

    // ---- phase A: copy enc->out (plain loads/stores; out absorbs into L3),
    //      sum(x^2), bf16 transpose into swizzled As. 16 float4/thread over
    //      128 rows x 256 ch.
    const int q4 = tid & 31;            // hw quad (4 hw rows), 0..31
    const int kg = tid >> 5;            // 0..15 -> ch0 = kg*16
    float sx = 0.f;
    {
        f32x4 vh[16];
        #pragma unroll
        for (int j = 0; j < 16; ++j)
            vh[j] = *(const f32x4*)(encB + (size_t)(kg * 16 + j) * 1024 + q4 * 4);
        #pragma unroll
        for (int j = 0; j < 16; ++j) {
            *(f32x4*)(outB + (size_t)(kg * 16 + j) * 1024 + q4 * 4) = vh[j];
            #pragma unroll
            for (int i2 = 0; i2 < 4; ++i2) sx = fmaf(vh[j][i2], vh[j][i2], sx);
        }
        #pragma unroll
        for (int i = 0; i < 4; ++i) {   // row r = q4*4+i (0..127); chunks 2kg,2kg+1
            unsigned short us[16];
            #pragma unroll
            for (int j = 0; j < 16; ++j) us[j] = f2bf(vh[j][i]);
            uint4 pk0, pk1;
            pk0.x = (unsigned)us[0]  | ((unsigned)us[1]  << 16);
            pk0.y = (unsigned)us[2]  | ((unsigned)us[3]  << 16);
            pk0.z = (unsigned)us[4]  | ((unsigned)us[5]  << 16);
            pk0.w = (unsigned)us[6]  | ((unsigned)us[7]  << 16);
            pk1.x = (unsigned)us[8]  | ((unsigned)us[9]  << 16);
            pk1.y = (unsigned)us[10] | ((unsigned)us[11] << 16);
            pk1.z = (unsigned)us[12] | ((unsigned)us[13] << 16);
            pk1.w = (unsigned)us[14] | ((unsigned)us[15] << 16);
            const int r = q4 * 4 + i;
            As[r * 32 + ((2 * kg + 0) ^ (r & 7))] = pk0;
            As[r * 32 + ((2 * kg + 1) ^ (r & 7))] = pk1;
        }
    }

    // ---- chunk-0 B prologue: issue now; the phase-A barrier's vmcnt(0)
    //      drain doubles as their completion wait (zero extra stall).
    Frag bfr[8];
    #pragma unroll
    for (int ks = 0; ks < 8; ++ks) bfr[ks].u4 = pc[ks * 256];

    #pragma unroll
    for (int m = 1; m <= 32; m <<= 1) sx += __shfl_xor(sx, m);
    if (lane == 0) partsA[w] = sx;
    __syncthreads();                    // As ready + chunk-0 B loaded

    // ---- A fragments: wave's 64-row group x full K into registers (mi=4) ----
    bf16x8 afr[4][8];
    #pragma unroll
    for (int mi = 0; mi < 4; ++mi) {
        const int r = wm * 64 + mi * 16 + c;
        #pragma unroll
        for (int ks = 0; ks < 8; ++ks) {
            Frag fa; fa.u4 = As[r * 32 + ((ks * 4 + q) ^ (r & 7))];
            afr[mi][ks] = fa.v;
        }
    }

    float rmin[4][4];
    #pragma unroll
    for (int mi = 0; mi < 4; ++mi)
        #pragma unroll
        for (int r2 = 0; r2 < 4; ++r2) rmin[mi][r2] = 1e30f;

    // ---- K-loop: 16 chunks of 64 codes; NO barriers, NO LDS; rolling
    //      global->reg prefetch one chunk ahead. ----
    for (int nc = 0; nc < 15; ++nc) CHUNK_BODY(nc, 1);
    CHUNK_BODY(15, 0);

    // min across the 16 code-columns (xor over c bits), then per-row mins
    #pragma unroll
    for (int mi = 0; mi < 4; ++mi)
        #pragma unroll
        for (int r2 = 0; r2 < 4; ++r2) {
            float x = rmin[mi][r2];
            x = fminf(x, __shfl_xor(x, 1));
            x = fminf(x, __shfl_xor(x, 2));
            x = fminf(x, __shfl_xor(x, 4));
            x = fminf(x, __shfl_xor(x, 8));
            rmin[mi][r2] = x;
        }
    if (c == 0) {
        #pragma unroll
        for (int mi = 0; mi < 4; ++mi)
            #pragma unroll
            for (int r2 = 0; r2 < 4; ++r2)
                dmin[wn][wm * 64 + mi * 16 + q * 4 + r2] = rmin[mi][r2];
    }
    __syncthreads();

    if (tid < 128) {
        float vr = fminf(fminf(dmin[0][tid], dmin[1][tid]),
                         fminf(dmin[2][tid], dmin[3][tid]));
        #pragma unroll
        for (int m = 1; m <= 32; m <<= 1) vr += __shfl_xor(vr, m);
        if ((tid & 63) == 0) partsB[tid >> 6] = vr;
    }
    __syncthreads();

    if (tid == 0) {
        float s = partsB[0] + partsB[1];
        #pragma unroll
        for (int w2 = 0; w2 < 8; ++w2) s += partsA[w2];
        atomicAdd(accum, s);
        __threadfence();                          // release our add
        unsigned prev = atomicAdd(done, 1u);      // device-scope ticket
        if (prev == NBLK - 1) {
            float tot = atomicAdd(accum, 0.0f);   // coherent read of total
            float cbl = tot * (1.0f / (float)ELEMS);
            out[ELEMS + 0] = 1.25f * cbl;   // loss = cbl + BETA*cbl
            out[ELEMS + 1] = cbl;           // codebook_loss
            out[ELEMS + 2] = cbl;           // commitment_loss
        }
    }
}

extern "C" void kernel_launch(void* const* d_in, const int* in_sizes, int n_in,
                              void* d_out, int out_size, void* d_ws, size_t ws_size,
                              hipStream_t stream) {
    const float* enc = (const float*)d_in[0];
    const float* cb  = (const float*)d_in[1];
    float* out = (float*)d_out;

    float*    accum = (float*)d_ws;                    // 4 B
    unsigned* done  = (unsigned*)((char*)d_ws + 64);   // 4 B
    float*    esq   = (float*)((char*)d_ws + 256);     // 4 KB
    uint2*    cbswz = (uint2*)((char*)d_ws + 8192);    // 512 KB

    vq_prep<<<dim3(256), dim3(256), 0, stream>>>(cb, cbswz, esq, accum, done);
    vq_main<<<dim3(NBLK), dim3(512), 0, stream>>>(enc, (const uint4*)cbswz, esq,
                                                  out, accum, done);
}

// Round 11
// 107.349 us; speedup vs baseline: 1.0498x; 1.0170x over previous
//
#include <hip/hip_runtime.h>
#include <stdint.h>

// ---------------------------------------------------------------------------
// VQ-VAE VectorQuantizer forward (MI355X):
//   out  = encoderout (faithful source bug)
//   loss_sum = sum_all x^2 + sum_m min_n (||e_n||^2 - 2 x_m.e_n)
//   cbl = loss_sum/ELEMS ; comm = cbl ; loss = 1.25*cbl
// enc [32,256,32,32] f32 NCHW, codebook [1024,256] f32.
// R12 = R11 + intra-block phase stagger. R11's block is serial: phase A
// (HBM ~10.2us device) then K-loop (L2 ~3.7us/group). Stagger: stage 1 =
// all 512 threads do rows 0..63; then waves 0-3 run their K-loop WHILE
// waves 4-7 do rows 64..127 (HBM streams under L2/MFMA work), group-local
// LDS-counter sync (4 waves, same block -> co-resident, no G16 issue),
// then waves 4-7 run their K-loop. Expected ~14us core vs ~17.6 serial.
// ---------------------------------------------------------------------------

#define EMB 256
#define ELEMS 8388608   // 32*256*32*32
#define NBLK 256

typedef __bf16 bf16x8 __attribute__((ext_vector_type(8)));
typedef float  f32x4  __attribute__((ext_vector_type(4)));

union Frag { uint4 u4; bf16x8 v; };

__device__ __forceinline__ unsigned short f2bf(float f) {
    unsigned u = __float_as_uint(f);
    u += 0x7FFFu + ((u >> 16) & 1u);   // RNE
    return (unsigned short)(u >> 16);
}

// ---------------------------------------------------------------------------
// prep: codebook f32 [1024][256] -> bf16 fragment-ordered global layout:
//   uint4 granule index = nc*2048 + ks*256 + (n&63)*4 + q
// esq[n] = ||e_n||^2. Also zeroes accum + done.
// ---------------------------------------------------------------------------
__global__ __launch_bounds__(256) void vq_prep(const float* __restrict__ cb,
                                               uint2* __restrict__ cbswz,
                                               float* __restrict__ esq,
                                               float* __restrict__ accum,
                                               unsigned* __restrict__ done) {
    if (blockIdx.x == 0 && threadIdx.x == 0) { accum[0] = 0.f; done[0] = 0u; }

    const int tid  = threadIdx.x;
    const int w    = tid >> 6;
    const int lane = tid & 63;
    const int n    = blockIdx.x * 4 + w;

    const float4* row = (const float4*)(cb + n * EMB);
    float4 v = row[lane];                       // k = 4*lane .. 4*lane+3

    float s = v.x * v.x + v.y * v.y + v.z * v.z + v.w * v.w;
    #pragma unroll
    for (int m = 1; m <= 32; m <<= 1) s += __shfl_xor(s, m);
    if (lane == 0) esq[n] = s;

    unsigned lo = (unsigned)f2bf(v.x) | ((unsigned)f2bf(v.y) << 16);
    unsigned hi = (unsigned)f2bf(v.z) | ((unsigned)f2bf(v.w) << 16);
    const int kc = lane >> 1;          // 16B K-granule 0..31 (8 bf16)
    const int h  = lane & 1;           // low/high uint2 of the granule
    const unsigned idx4 = ((unsigned)(n >> 6) << 11) + ((unsigned)(kc >> 2) << 8)
                        + ((unsigned)(n & 63) << 2) + (unsigned)(kc & 3);
    cbswz[idx4 * 2 + h] = make_uint2(lo, hi);
}

// ---------------------------------------------------------------------------
// main: block = 128 hw-rows of one image; 8 waves; grid 256 (1 block/CU).
// wm = w>>2: 64-row group; wn = w&3: 16-code subgroup.
// ---------------------------------------------------------------------------

#define CHUNK_BODY(nc_, LOADNEXT_) do {                                        \
    f32x4 _a0 = (f32x4){0.f,0.f,0.f,0.f};                                      \
    f32x4 _a1 = (f32x4){0.f,0.f,0.f,0.f};                                      \
    f32x4 _a2 = (f32x4){0.f,0.f,0.f,0.f};                                      \
    f32x4 _a3 = (f32x4){0.f,0.f,0.f,0.f};                                      \
    _Pragma("unroll")                                                          \
    for (int _ks = 0; _ks < 8; ++_ks) {                                        \
        bf16x8 _bv = bfr[_ks].v;                                               \
        _a0 = __builtin_amdgcn_mfma_f32_16x16x32_bf16(afr[0][_ks], _bv, _a0, 0, 0, 0); \
        _a1 = __builtin_amdgcn_mfma_f32_16x16x32_bf16(afr[1][_ks], _bv, _a1, 0, 0, 0); \
        _a2 = __builtin_amdgcn_mfma_f32_16x16x32_bf16(afr[2][_ks], _bv, _a2, 0, 0, 0); \
        _a3 = __builtin_amdgcn_mfma_f32_16x16x32_bf16(afr[3][_ks], _bv, _a3, 0, 0, 0); \
        if (LOADNEXT_)   /* rolling prefetch: chunk nc+1, same frag slot */    \
            bfr[_ks].u4 = pc[((nc_) + 1) * 2048 + _ks * 256];                  \
    }                                                                          \
    const float _eq = esq[(nc_) * 64 + nl];                                    \
    _Pragma("unroll")                                                          \
    for (int _r2 = 0; _r2 < 4; ++_r2) {                                        \
        rmin[0][_r2] = fminf(rmin[0][_r2], fmaf(-2.f, _a0[_r2], _eq));         \
        rmin[1][_r2] = fminf(rmin[1][_r2], fmaf(-2.f, _a1[_r2], _eq));         \
        rmin[2][_r2] = fminf(rmin[2][_r2], fmaf(-2.f, _a2[_r2], _eq));         \
        rmin[3][_r2] = fminf(rmin[3][_r2], fmaf(-2.f, _a3[_r2], _eq));         \
    } } while (0)

#define EXTRACT_AFR(rbase_) do {                                               \
    _Pragma("unroll")                                                          \
    for (int _mi = 0; _mi < 4; ++_mi) {                                        \
        const int _r = (rbase_) + _mi * 16 + c;                                \
        _Pragma("unroll")                                                      \
        for (int _ks = 0; _ks < 8; ++_ks) {                                    \
            Frag _fa; _fa.u4 = As[_r * 32 + ((_ks * 4 + q) ^ (_r & 7))];       \
            afr[_mi][_ks] = _fa.v;                                             \
        }                                                                      \
    } } while (0)

__global__ __launch_bounds__(512, 2)
void vq_main(const float* __restrict__ enc,
             const uint4* __restrict__ cbswz,
             const float* __restrict__ esq,
             float* __restrict__ out,
             float* __restrict__ accum,
             unsigned* __restrict__ done) {
    __shared__ uint4 As[4096];          // 64 KB: 128 rows x 512B swizzled
    __shared__ float dmin[4][128];
    __shared__ float partsA[8];
    __shared__ float partsB[2];
    __shared__ unsigned g1cnt;

    const int tid  = threadIdx.x;
    const int w    = tid >> 6;          // wave 0..7
    const int lane = tid & 63;
    const int q    = lane >> 4;         // quad 0..3
    const int c    = lane & 15;
    const int wm   = w >> 2;            // 0..1 (64-row group)
    const int wn   = w & 3;             // 0..3 (16-code subgroup)

    const int b   = blockIdx.x >> 3;            // image
    const int hw0 = (blockIdx.x & 7) << 7;      // 128-row slab
    const float* encB = enc + (size_t)b * 262144 + hw0;
    float*       outB = out + (size_t)b * 262144 + hw0;

    const int nl = wn * 16 + c;         // this lane's code within each 64-chunk
    const uint4* pc = cbswz + (size_t)(nl * 4 + q);   // per-lane frag base

    if (tid == 0) g1cnt = 0u;

    // ---- stage 1: ALL 512 threads, rows 0..63 (copy + sumsq + transpose) ----
    const int q4s = tid & 15;           // row quad 0..15 -> rows q4s*4..+3
    const int kgs = tid >> 4;           // 0..31 -> channels kgs*8..+7 (= chunk kgs)
    float sx = 0.f;
    {
        f32x4 vh[8];
        #pragma unroll
        for (int j = 0; j < 8; ++j)
            vh[j] = *(const f32x4*)(encB + (size_t)(kgs * 8 + j) * 1024 + q4s * 4);
        #pragma unroll
        for (int j = 0; j < 8; ++j) {
            *(f32x4*)(outB + (size_t)(kgs * 8 + j) * 1024 + q4s * 4) = vh[j];
            #pragma unroll
            for (int i2 = 0; i2 < 4; ++i2) sx = fmaf(vh[j][i2], vh[j][i2], sx);
        }
        #pragma unroll
        for (int i = 0; i < 4; ++i) {   // row r = q4s*4+i (0..63); chunk kgs
            unsigned short us[8];
            #pragma unroll
            for (int j = 0; j < 8; ++j) us[j] = f2bf(vh[j][i]);
            uint4 pk;
            pk.x = (unsigned)us[0] | ((unsigned)us[1] << 16);
            pk.y = (unsigned)us[2] | ((unsigned)us[3] << 16);
            pk.z = (unsigned)us[4] | ((unsigned)us[5] << 16);
            pk.w = (unsigned)us[6] | ((unsigned)us[7] << 16);
            const int r = q4s * 4 + i;
            As[r * 32 + (kgs ^ (r & 7))] = pk;
        }
    }

    Frag bfr[8];
    if (wm == 0) {                      // group-0 B prologue under the barrier
        #pragma unroll
        for (int ks = 0; ks < 8; ++ks) bfr[ks].u4 = pc[ks * 256];
    }
    __syncthreads();                    // rows 0..63 ready (+ g1cnt init)

    bf16x8 afr[4][8];
    float rmin[4][4];
    #pragma unroll
    for (int mi = 0; mi < 4; ++mi)
        #pragma unroll
        for (int r2 = 0; r2 < 4; ++r2) rmin[mi][r2] = 1e30f;

    if (wm == 0) {
        // ---- group 0: K-loop over rows 0..63 immediately ----
        EXTRACT_AFR(0);
        for (int nc = 0; nc < 15; ++nc) CHUNK_BODY(nc, 1);
        CHUNK_BODY(15, 0);
    } else {
        // ---- group 1 (waves 4..7): stage 2 = rows 64..127, then K-loop.
        //      HBM streaming here overlaps group 0's L2/MFMA K-loop. ----
        const int tid2 = tid - 256;
        const int q42 = tid2 & 15;      // rows 64 + q42*4 ..+3
        const int kg2 = tid2 >> 4;      // 0..15 -> channels kg2*16..+15
        {
            f32x4 vh[16];
            #pragma unroll
            for (int j = 0; j < 16; ++j)
                vh[j] = *(const f32x4*)(encB + (size_t)(kg2 * 16 + j) * 1024 + 64 + q42 * 4);
            #pragma unroll
            for (int j = 0; j < 16; ++j) {
                *(f32x4*)(outB + (size_t)(kg2 * 16 + j) * 1024 + 64 + q42 * 4) = vh[j];
                #pragma unroll
                for (int i2 = 0; i2 < 4; ++i2) sx = fmaf(vh[j][i2], vh[j][i2], sx);
            }
            #pragma unroll
            for (int i = 0; i < 4; ++i) {   // row r = 64+q42*4+i; chunks 2kg2,2kg2+1
                unsigned short us[16];
                #pragma unroll
                for (int j = 0; j < 16; ++j) us[j] = f2bf(vh[j][i]);
                uint4 pk0, pk1;
                pk0.x = (unsigned)us[0]  | ((unsigned)us[1]  << 16);
                pk0.y = (unsigned)us[2]  | ((unsigned)us[3]  << 16);
                pk0.z = (unsigned)us[4]  | ((unsigned)us[5]  << 16);
                pk0.w = (unsigned)us[6]  | ((unsigned)us[7]  << 16);
                pk1.x = (unsigned)us[8]  | ((unsigned)us[9]  << 16);
                pk1.y = (unsigned)us[10] | ((unsigned)us[11] << 16);
                pk1.z = (unsigned)us[12] | ((unsigned)us[13] << 16);
                pk1.w = (unsigned)us[14] | ((unsigned)us[15] << 16);
                const int r = 64 + q42 * 4 + i;
                As[r * 32 + ((2 * kg2 + 0) ^ (r & 7))] = pk0;
                As[r * 32 + ((2 * kg2 + 1) ^ (r & 7))] = pk1;
            }
        }
        #pragma unroll
        for (int ks = 0; ks < 8; ++ks) bfr[ks].u4 = pc[ks * 256];

        // group-local sync: 4 waves of group 1 only (all same block ->
        // co-resident; no cross-block assumption)
        __threadfence_block();          // drain LDS writes
        if (lane == 0) atomicAdd(&g1cnt, 1u);
        while (*(volatile unsigned*)&g1cnt < 4u)
            __builtin_amdgcn_s_sleep(2);
        __builtin_amdgcn_sched_barrier(0);      // no hoisting past the spin
        asm volatile("" ::: "memory");

        EXTRACT_AFR(64);
        for (int nc = 0; nc < 15; ++nc) CHUNK_BODY(nc, 1);
        CHUNK_BODY(15, 0);
    }

    // min across the 16 code-columns (xor over c bits), then per-row mins
    #pragma unroll
    for (int mi = 0; mi < 4; ++mi)
        #pragma unroll
        for (int r2 = 0; r2 < 4; ++r2) {
            float x = rmin[mi][r2];
            x = fminf(x, __shfl_xor(x, 1));
            x = fminf(x, __shfl_xor(x, 2));
            x = fminf(x, __shfl_xor(x, 4));
            x = fminf(x, __shfl_xor(x, 8));
            rmin[mi][r2] = x;
        }
    if (c == 0) {
        #pragma unroll
        for (int mi = 0; mi < 4; ++mi)
            #pragma unroll
            for (int r2 = 0; r2 < 4; ++r2)
                dmin[wn][wm * 64 + mi * 16 + q * 4 + r2] = rmin[mi][r2];
    }
    #pragma unroll
    for (int m = 1; m <= 32; m <<= 1) sx += __shfl_xor(sx, m);
    if (lane == 0) partsA[w] = sx;
    __syncthreads();

    if (tid < 128) {
        float vr = fminf(fminf(dmin[0][tid], dmin[1][tid]),
                         fminf(dmin[2][tid], dmin[3][tid]));
        #pragma unroll
        for (int m = 1; m <= 32; m <<= 1) vr += __shfl_xor(vr, m);
        if ((tid & 63) == 0) partsB[tid >> 6] = vr;
    }
    __syncthreads();

    if (tid == 0) {
        float s = partsB[0] + partsB[1];
        #pragma unroll
        for (int w2 = 0; w2 < 8; ++w2) s += partsA[w2];
        atomicAdd(accum, s);
        __threadfence();                          // release our add
        unsigned prev = atomicAdd(done, 1u);      // device-scope ticket
        if (prev == NBLK - 1) {
            float tot = atomicAdd(accum, 0.0f);   // coherent read of total
            float cbl = tot * (1.0f / (float)ELEMS);
            out[ELEMS + 0] = 1.25f * cbl;   // loss = cbl + BETA*cbl
            out[ELEMS + 1] = cbl;           // codebook_loss
            out[ELEMS + 2] = cbl;           // commitment_loss
        }
    }
}

extern "C" void kernel_launch(void* const* d_in, const int* in_sizes, int n_in,
                              void* d_out, int out_size, void* d_ws, size_t ws_size,
                              hipStream_t stream) {
    const float* enc = (const float*)d_in[0];
    const float* cb  = (const float*)d_in[1];
    float* out = (float*)d_out;

    float*    accum = (float*)d_ws;                    // 4 B
    unsigned* done  = (unsigned*)((char*)d_ws + 64);   // 4 B
    float*    esq   = (float*)((char*)d_ws + 256);     // 4 KB
    uint2*    cbswz = (uint2*)((char*)d_ws + 8192);    // 512 KB

    vq_prep<<<dim3(256), dim3(256), 0, stream>>>(cb, cbswz, esq, accum, done);
    vq_main<<<dim3(NBLK), dim3(512), 0, stream>>>(enc, (const uint4*)cbswz, esq,
                                                  out, accum, done);
}